// Round 8
// baseline (790.562 us; speedup 1.0000x reference)
//
#include <hip/hip_runtime.h>

#define B 8
#define C 64
#define N 4096
#define O 64
#define KNN 20
#define PQ 4
#define BN_EPS 1e-5f
#define NEG_SLOPE 0.2f

typedef _Float16 f16x8 __attribute__((ext_vector_type(8)));
typedef float    f32x4 __attribute__((ext_vector_type(4)));
#define MFMA16(a, b, c) __builtin_amdgcn_mfma_f32_16x16x32_f16(a, b, c, 0, 0, 0)

__device__ __forceinline__ void gld16(const float* g, float* l) {
    __builtin_amdgcn_global_load_lds((const __attribute__((address_space(1))) void*)g,
                                     (__attribute__((address_space(3))) void*)l, 16, 0, 0);
}

// insert (r,m) into ascending-sorted top-KNN list, dropping old min d[0].
// precondition: r > d[0]. Tie-safe (multiset semantics).
__device__ __forceinline__ void sorted_insert(float (&d)[KNN], int (&id)[KNN],
                                              float r, int m) {
    bool cp = true;
    #pragma unroll
    for (int j = 0; j < KNN - 1; ++j) {
        bool c = d[j + 1] < r;
        float nv = c ? d[j + 1] : (cp ? r : d[j]);
        int   ni = c ? id[j + 1] : (cp ? m : id[j]);
        d[j] = nv; id[j] = ni;
        cp = c;
    }
    d[KNN - 1]  = cp ? r : d[KNN - 1];
    id[KNN - 1] = cp ? m : id[KNN - 1];
}

// -------- K0: x (B,C,N) -> Xt (B,N,C) fp32, sq = ||x_n||^2, and AHL: f16 hi/lo
// frag-major: per 16-row group (4096 B): [term][khalf][quad][slot16][8 f16]
__global__ __launch_bounds__(256) void k_transpose(const float* __restrict__ x,
                                                   float* __restrict__ Xt,
                                                   float* __restrict__ sq,
                                                   char* __restrict__ AHL) {
    __shared__ float lds[C][65];
    int b    = blockIdx.x >> 6;
    int n0   = (blockIdx.x & 63) << 6;
    int lane = threadIdx.x & 63;
    int w    = threadIdx.x >> 6;
    #pragma unroll
    for (int i = 0; i < 16; ++i) {
        int c = w * 16 + i;
        lds[c][lane] = x[(size_t)b * C * N + (size_t)c * N + n0 + lane];
    }
    __syncthreads();
    #pragma unroll
    for (int i = 0; i < 16; ++i) {
        int nl = w * 16 + i;
        float v = lds[lane][nl];
        Xt[(size_t)b * N * C + (size_t)(n0 + nl) * C + lane] = v;
        float s = v * v;
        #pragma unroll
        for (int off = 32; off; off >>= 1) s += __shfl_xor(s, off, 64);
        if (lane == 0) sq[b * N + n0 + nl] = s;
    }
    int s2  = threadIdx.x & 15;
    int rem = threadIdx.x >> 4;
    int qd  = rem & 3;
    int hh  = (rem >> 2) & 1;
    int tt  = rem >> 3;
    int kb  = hh * 32 + qd * 8;
    for (int i = 0; i < 4; ++i) {
        int rowl = i * 16 + s2;
        f16x8 pk;
        #pragma unroll
        for (int ii = 0; ii < 8; ++ii) {
            float v = lds[kb + ii][rowl];
            _Float16 hv = (_Float16)v;
            if (tt) hv = (_Float16)(v - (float)hv);
            pk[ii] = hv;
        }
        char* dst = AHL + ((size_t)b << 20) + (size_t)((n0 >> 4) + i) * 4096
                  + tt * 2048 + hh * 1024 + qd * 256 + s2 * 16;
        *(f16x8*)dst = pk;
    }
}

// -------- K1: a = X*(W1-W2)^T, bvec = X*W2^T
__global__ __launch_bounds__(256, 2) void k_ab(const float* __restrict__ Xt,
                                               const float* __restrict__ W,
                                               float* __restrict__ av,
                                               float* __restrict__ bv) {
    int b  = blockIdx.x >> 5;
    int n0 = (blockIdx.x & 31) << 7;
    int o  = threadIdx.x & 63;
    int w  = __builtin_amdgcn_readfirstlane((int)(threadIdx.x >> 6));
    float wa[C], wb[C];
    #pragma unroll
    for (int c = 0; c < C; ++c) {
        float w1 = W[o * 2 * C + c];
        float w2 = W[o * 2 * C + C + c];
        wa[c] = w1 - w2;
        wb[c] = w2;
    }
    const float* xb = Xt + (size_t)b * N * C;
    for (int i = 0; i < 32; ++i) {
        int n = n0 + w * 32 + i;
        const float* xr = xb + (size_t)n * C;
        float aa = 0.f, bb = 0.f;
        #pragma unroll
        for (int c = 0; c < C; ++c) {
            float xc = xr[c];
            aa = fmaf(xc, wa[c], aa);
            bb = fmaf(xc, wb[c], bb);
        }
        size_t oidx = ((size_t)b * N + n) * O + o;
        av[oidx] = aa;
        bv[oidx] = bb;
    }
}

// -------- K2: MFMA + in-register top-20 on MFMA output.
// block bid -> (b, rb, half h). Wave w owns queries rb*64 + w*16 .. +16.
// Per 64-cand tile, wave does 4 cand-groups x 6 MFMAs; each lane's acc rows
// are 4 cands of ITS query (col=lane&15) -> register pending-queue top-k.
// One barrier per tile (cand-buffer dbuf). Quad-merge in-wave at the end.
__global__ __launch_bounds__(256, 3) void k_knn(const char* __restrict__ AHL,
                                                const float* __restrict__ sq,
                                                float* __restrict__ pdg,
                                                int* __restrict__ pig) {
    __shared__ __align__(16) char smem[43008];   // dbuf 32 KB; merge overlay 42 KB
    char* cb0 = smem;
    char* cb1 = smem + 16384;

    int bid  = blockIdx.x;
    int h    = bid & 1;
    int rb   = (bid >> 1) & 63;
    int b    = bid >> 7;
    int tid  = threadIdx.x;
    int lane = tid & 63;
    int w    = __builtin_amdgcn_readfirstlane(tid >> 6);
    int quad = lane >> 4;
    const char*  AHLb = AHL + ((size_t)b << 20);
    const float* sqb  = sq + b * N;
    int cbase0 = h * (N / 2);                    // candidate half base
    const char* Asrc = AHLb + (size_t)cbase0 * 256;  // 16 KB per 64-cand tile

    // B-frags: this wave's query group (rb*4 + w): hi/lo x khalf (16 VGPRs)
    const char* qb = AHLb + (size_t)(rb * 4 + w) * 4096 + lane * 16;
    f16x8 bh0 = *(const f16x8*)(qb);
    f16x8 bh1 = *(const f16x8*)(qb + 1024);
    f16x8 bl0 = *(const f16x8*)(qb + 2048);
    f16x8 bl1 = *(const f16x8*)(qb + 3072);

    float d[KNN]; int id[KNN];
    #pragma unroll
    for (int j = 0; j < KNN; ++j) { d[j] = -3.4e38f; id[j] = 0; }
    float pv[PQ]; int pi[PQ]; int pc = 0;
    #pragma unroll
    for (int j = 0; j < PQ; ++j) { pv[j] = 0.f; pi[j] = 0; }

    // prestage tile 0 into cb0 (wave w stages 4 KB)
    #pragma unroll
    for (int j2 = 0; j2 < 4; ++j2) {
        int ch = (w * 4 + j2) * 1024 + lane * 16;
        gld16((const float*)(Asrc + ch), (float*)(cb0 + ch));
    }
    __syncthreads();

    for (int t = 0; t < 32; ++t) {
        const char* cur = (t & 1) ? cb1 : cb0;
        char*       nxt = (t & 1) ? cb0 : cb1;
        if (t + 1 < 32) {                      // async-stage next tile
            const char* src = Asrc + (size_t)(t + 1) * 16384;
            #pragma unroll
            for (int j2 = 0; j2 < 4; ++j2) {
                int ch = (w * 4 + j2) * 1024 + lane * 16;
                gld16((const float*)(src + ch), (float*)(nxt + ch));
            }
        }
        #pragma unroll 1
        for (int cg = 0; cg < 4; ++cg) {
            const char* ct = cur + cg * 4096 + lane * 16;
            f16x8 ah0 = *(const f16x8*)(ct);
            f16x8 ah1 = *(const f16x8*)(ct + 1024);
            f16x8 al0 = *(const f16x8*)(ct + 2048);
            f16x8 al1 = *(const f16x8*)(ct + 3072);
            f32x4 acc = {0.f, 0.f, 0.f, 0.f};
            acc = MFMA16(ah0, bh0, acc);
            acc = MFMA16(ah1, bh1, acc);
            acc = MFMA16(ah0, bl0, acc);
            acc = MFMA16(ah1, bl1, acc);
            acc = MFMA16(al0, bh0, acc);
            acc = MFMA16(al1, bh1, acc);
            int c0 = cbase0 + t * 64 + cg * 16 + quad * 4;   // lane's 4 cands
            float4 sqv = *(const float4*)(sqb + c0);
            #pragma unroll
            for (int r = 0; r < 4; ++r) {
                float sc = fmaf(2.f, acc[r],
                                -((r == 0) ? sqv.x : (r == 1) ? sqv.y
                                           : (r == 2) ? sqv.z : sqv.w));
                if (sc > d[0]) {               // cheap append to pending queue
                    #pragma unroll
                    for (int j = 0; j < PQ; ++j) {
                        bool sel = (pc == j);
                        pv[j] = sel ? sc : pv[j];
                        pi[j] = sel ? (c0 + r) : pi[j];
                    }
                    ++pc;
                }
                if (__any(pc == PQ)) {         // drain all lanes in parallel
                    #pragma unroll
                    for (int j = 0; j < PQ; ++j)
                        if (j < pc && pv[j] > d[0]) sorted_insert(d, id, pv[j], pi[j]);
                    pc = 0;
                }
            }
        }
        __syncthreads();   // drains async stage; protects cur for restage
    }
    #pragma unroll
    for (int j = 0; j < PQ; ++j)               // final flush
        if (j < pc && pv[j] > d[0]) sorted_insert(d, id, pv[j], pi[j]);

    // in-wave quad merge: query col = lane&15; union the 4 quads' cand slices
    __syncthreads();
    float* md = (float*)smem;                  // [4][64][21] floats (stride 21)
    int*   mi = (int*)(smem + 21504);
    int base = (w * 64 + lane) * 21;
    #pragma unroll
    for (int j = 0; j < KNN; ++j) { md[base + j] = d[j]; mi[base + j] = id[j]; }
    __syncthreads();
    if (lane < 16) {
        for (int q = 1; q < 4; ++q) {
            const float* lp = md + (w * 64 + q * 16 + lane) * 21;
            const int*   lq = mi + (w * 64 + q * 16 + lane) * 21;
            for (int j = KNN - 1; j >= 0; --j) {   // descending; early-exit
                float r = lp[j];
                if (!__any(r > d[0])) break;
                if (r > d[0]) sorted_insert(d, id, r, lq[j]);
            }
        }
        size_t rr = (size_t)b * N + rb * 64 + w * 16 + lane;
        float* po = pdg + (rr * 2 + h) * KNN;
        int*   qo = pig + (rr * 2 + h) * KNN;
        #pragma unroll
        for (int j = 0; j < KNN; ++j) { po[j] = d[j]; qo[j] = id[j]; }
    }
}

// -------- K2b: merge the 2 sorted half-lists per query -> knn indices
__global__ __launch_bounds__(128) void k_merge(const float* __restrict__ pdg,
                                               const int* __restrict__ pig,
                                               int* __restrict__ knn) {
    __shared__ float sd[128][41];
    __shared__ int   si[128][41];
    int t = threadIdx.x;
    size_t rr = (size_t)blockIdx.x * 128 + t;
    const float* pr = pdg + rr * (2 * KNN);
    const int*   qr = pig + rr * (2 * KNN);
    #pragma unroll
    for (int j = 0; j < 2 * KNN; ++j) { sd[t][j] = pr[j]; si[t][j] = qr[j]; }
    int i = KNN - 1, j = KNN - 1;
    int* op = knn + rr * KNN;
    for (int o = 0; o < KNN; ++o) {
        bool t0 = (j < 0) || (i >= 0 && sd[t][i] >= sd[t][KNN + j]);
        op[o] = t0 ? si[t][i] : si[t][KNN + j];
        if (t0) --i; else --j;
    }
}

// -------- K3: out[b][o][n] = leaky(scale*(a[n][o] + max_k bvec[idx_k][o]) + bias)
__global__ __launch_bounds__(256) void k_out(const float* __restrict__ av,
                                             const float* __restrict__ bv,
                                             const int* __restrict__ knn,
                                             const float* __restrict__ gamma,
                                             const float* __restrict__ beta,
                                             const float* __restrict__ rmean,
                                             const float* __restrict__ rvar,
                                             float* __restrict__ out) {
    __shared__ float lds[64][65];
    int b    = blockIdx.x >> 6;
    int n0   = (blockIdx.x & 63) << 6;
    int lane = threadIdx.x & 63;
    int w    = __builtin_amdgcn_readfirstlane((int)(threadIdx.x >> 6));
    int o    = lane;
    float scale = gamma[o] * rsqrtf(rvar[o] + BN_EPS);
    float bias  = fmaf(-rmean[o], scale, beta[o]);
    const float* bvb = bv + (size_t)b * N * O;
    for (int i = 0; i < 16; ++i) {
        int n = n0 + w * 16 + i;
        const int* kn = knn + ((size_t)b * N + n) * KNN;
        float mx = -3.4e38f, mn = 3.4e38f;
        #pragma unroll
        for (int j = 0; j < KNN; ++j) {
            float v = bvb[(size_t)kn[j] * O + o];
            mx = fmaxf(mx, v);
            mn = fminf(mn, v);
        }
        float a   = av[((size_t)b * N + n) * O + o];
        float sel = (scale >= 0.f) ? (a + mx) : (a + mn);
        float y   = fmaf(sel, scale, bias);
        y = fmaxf(y, NEG_SLOPE * y);
        lds[o][w * 16 + i] = y;
    }
    __syncthreads();
    int r  = threadIdx.x >> 2;
    int c0 = (threadIdx.x & 3) << 4;
    float* ob = out + (size_t)b * O * N + (size_t)r * N + n0;
    #pragma unroll
    for (int j = 0; j < 16; j += 4) {
        float4 v;
        v.x = lds[r][c0 + j + 0];
        v.y = lds[r][c0 + j + 1];
        v.z = lds[r][c0 + j + 2];
        v.w = lds[r][c0 + j + 3];
        *(float4*)(ob + c0 + j) = v;
    }
}

extern "C" void kernel_launch(void* const* d_in, const int* in_sizes, int n_in,
                              void* d_out, int out_size, void* d_ws, size_t ws_size,
                              hipStream_t stream) {
    const float* x     = (const float*)d_in[0];
    const float* W     = (const float*)d_in[1];
    const float* gamma = (const float*)d_in[2];
    const float* beta  = (const float*)d_in[3];
    const float* rmean = (const float*)d_in[4];
    const float* rvar  = (const float*)d_in[5];
    float* out = (float*)d_out;

    char* wsb = (char*)d_ws;
    float* Xt  = (float*)(wsb);                 //  8 MB
    float* sqn = (float*)(wsb + 8388608);       //  128 KB
    float* av  = (float*)(wsb + 8519680);       //  8 MB
    float* bvv = (float*)(wsb + 16908288);      //  8 MB
    int*   knn = (int*)  (wsb + 25296896);      //  2.5 MB
    char*  AHL =         (wsb + 27918336);      //  8 MB f16 hi/lo frag-major
    float* pdg = (float*)(wsb + 36306944);      //  5.24 MB partial dists
    int*   pig = (int*)  (wsb + 41549824);      //  5.24 MB partial ids

    k_transpose<<<512, 256, 0, stream>>>(x, Xt, sqn, AHL);
    k_ab<<<256, 256, 0, stream>>>(Xt, W, av, bvv);
    k_knn<<<1024, 256, 0, stream>>>(AHL, sqn, pdg, pig);
    k_merge<<<256, 128, 0, stream>>>(pdg, pig, knn);
    k_out<<<512, 256, 0, stream>>>(av, bvv, knn, gamma, beta, rmean, rvar, out);
}

// Round 9
// 685.013 us; speedup vs baseline: 1.1541x; 1.1541x over previous
//
#include <hip/hip_runtime.h>

#define B 8
#define C 64
#define N 4096
#define O 64
#define KNN 20
#define PQ 4
#define BN_EPS 1e-5f
#define NEG_SLOPE 0.2f

typedef _Float16 f16x8 __attribute__((ext_vector_type(8)));
typedef float    f32x4 __attribute__((ext_vector_type(4)));
#define MFMA16(a, b, c) __builtin_amdgcn_mfma_f32_16x16x32_f16(a, b, c, 0, 0, 0)

// insert (r,m) into ascending-sorted top-KNN list, dropping old min d[0].
// precondition: r > d[0]. Tie-safe (multiset semantics).
__device__ __forceinline__ void sorted_insert(float (&d)[KNN], int (&id)[KNN],
                                              float r, int m) {
    bool cp = true;
    #pragma unroll
    for (int j = 0; j < KNN - 1; ++j) {
        bool c = d[j + 1] < r;
        float nv = c ? d[j + 1] : (cp ? r : d[j]);
        int   ni = c ? id[j + 1] : (cp ? m : id[j]);
        d[j] = nv; id[j] = ni;
        cp = c;
    }
    d[KNN - 1]  = cp ? r : d[KNN - 1];
    id[KNN - 1] = cp ? m : id[KNN - 1];
}

// -------- K0: x (B,C,N) -> Xt (B,N,C) fp32, sq = ||x_n||^2, and AHL: f16 hi/lo
// frag-major: per 16-row group (4096 B): [term][khalf][quad][slot16][8 f16]
__global__ __launch_bounds__(256) void k_transpose(const float* __restrict__ x,
                                                   float* __restrict__ Xt,
                                                   float* __restrict__ sq,
                                                   char* __restrict__ AHL) {
    __shared__ float lds[C][65];
    int b    = blockIdx.x >> 6;
    int n0   = (blockIdx.x & 63) << 6;
    int lane = threadIdx.x & 63;
    int w    = threadIdx.x >> 6;
    #pragma unroll
    for (int i = 0; i < 16; ++i) {
        int c = w * 16 + i;
        lds[c][lane] = x[(size_t)b * C * N + (size_t)c * N + n0 + lane];
    }
    __syncthreads();
    #pragma unroll
    for (int i = 0; i < 16; ++i) {
        int nl = w * 16 + i;
        float v = lds[lane][nl];
        Xt[(size_t)b * N * C + (size_t)(n0 + nl) * C + lane] = v;
        float s = v * v;
        #pragma unroll
        for (int off = 32; off; off >>= 1) s += __shfl_xor(s, off, 64);
        if (lane == 0) sq[b * N + n0 + nl] = s;
    }
    int s2  = threadIdx.x & 15;
    int rem = threadIdx.x >> 4;
    int qd  = rem & 3;
    int hh  = (rem >> 2) & 1;
    int tt  = rem >> 3;
    int kb  = hh * 32 + qd * 8;
    for (int i = 0; i < 4; ++i) {
        int rowl = i * 16 + s2;
        f16x8 pk;
        #pragma unroll
        for (int ii = 0; ii < 8; ++ii) {
            float v = lds[kb + ii][rowl];
            _Float16 hv = (_Float16)v;
            if (tt) hv = (_Float16)(v - (float)hv);
            pk[ii] = hv;
        }
        char* dst = AHL + ((size_t)b << 20) + (size_t)((n0 >> 4) + i) * 4096
                  + tt * 2048 + hh * 1024 + qd * 256 + s2 * 16;
        *(f16x8*)dst = pk;
    }
}

// -------- K1: a = X*(W1-W2)^T, bvec = X*W2^T
__global__ __launch_bounds__(256, 2) void k_ab(const float* __restrict__ Xt,
                                               const float* __restrict__ W,
                                               float* __restrict__ av,
                                               float* __restrict__ bv) {
    int b  = blockIdx.x >> 5;
    int n0 = (blockIdx.x & 31) << 7;
    int o  = threadIdx.x & 63;
    int w  = __builtin_amdgcn_readfirstlane((int)(threadIdx.x >> 6));
    float wa[C], wb[C];
    #pragma unroll
    for (int c = 0; c < C; ++c) {
        float w1 = W[o * 2 * C + c];
        float w2 = W[o * 2 * C + C + c];
        wa[c] = w1 - w2;
        wb[c] = w2;
    }
    const float* xb = Xt + (size_t)b * N * C;
    for (int i = 0; i < 32; ++i) {
        int n = n0 + w * 32 + i;
        const float* xr = xb + (size_t)n * C;
        float aa = 0.f, bb = 0.f;
        #pragma unroll
        for (int c = 0; c < C; ++c) {
            float xc = xr[c];
            aa = fmaf(xc, wa[c], aa);
            bb = fmaf(xc, wb[c], bb);
        }
        size_t oidx = ((size_t)b * N + n) * O + o;
        av[oidx] = aa;
        bv[oidx] = bb;
    }
}

// -------- K2: barrier-free streaming MFMA kNN. Zero LDS, zero __syncthreads.
// bid = rb*16 + b*2 + h (XCD-locality swizzle: round-robin XCD assignment sees
// only 2 (b,h) cand-halves -> ~1.6 MB L2 working set). Wave w owns queries
// rb*64 + w*16..+16; lane quad q scans cand slice q. A-frags streamed from
// global (coalesced, L2-hit) with 1-deep manual prefetch. Top-k fully in regs.
__global__ __launch_bounds__(256, 3) void k_knn(const char* __restrict__ AHL,
                                                const float* __restrict__ sq,
                                                float* __restrict__ pdg,
                                                int* __restrict__ pig) {
    int bid  = blockIdx.x;
    int rb   = bid >> 4;
    int b    = (bid >> 1) & 7;
    int h    = bid & 1;
    int tid  = threadIdx.x;
    int lane = tid & 63;
    int w    = __builtin_amdgcn_readfirstlane(tid >> 6);
    int quad = lane >> 4;
    const char*  AHLb = AHL + ((size_t)b << 20);
    const float* sqb  = sq + b * N;
    int cbase0 = h * (N / 2);
    const char* Asrc = AHLb + (size_t)cbase0 * 256;

    // B-frags: this wave's query group (rb*4 + w): hi/lo x khalf (16 VGPRs)
    const char* qb = AHLb + (size_t)(rb * 4 + w) * 4096 + lane * 16;
    f16x8 bh0 = *(const f16x8*)(qb);
    f16x8 bh1 = *(const f16x8*)(qb + 1024);
    f16x8 bl0 = *(const f16x8*)(qb + 2048);
    f16x8 bl1 = *(const f16x8*)(qb + 3072);

    float d[KNN]; int id[KNN];
    #pragma unroll
    for (int j = 0; j < KNN; ++j) { d[j] = -3.4e38f; id[j] = 0; }
    float pv[PQ]; int pi[PQ]; int pc = 0;
    #pragma unroll
    for (int j = 0; j < PQ; ++j) { pv[j] = 0.f; pi[j] = 0; }

    // prefetch iter 0
    const char* p0 = Asrc + lane * 16;
    f16x8 na0 = *(const f16x8*)(p0);
    f16x8 na1 = *(const f16x8*)(p0 + 1024);
    f16x8 na2 = *(const f16x8*)(p0 + 2048);
    f16x8 na3 = *(const f16x8*)(p0 + 3072);
    float4 nsq = *(const float4*)(sqb + cbase0 + quad * 4);

    #pragma unroll 1
    for (int it = 0; it < 128; ++it) {         // 16 cands per iter
        f16x8 a0 = na0, a1 = na1, a2 = na2, a3 = na3;
        float4 sqv = nsq;
        if (it + 1 < 128) {                    // issue next-iter loads early
            const char* p = Asrc + (size_t)(it + 1) * 4096 + lane * 16;
            na0 = *(const f16x8*)(p);
            na1 = *(const f16x8*)(p + 1024);
            na2 = *(const f16x8*)(p + 2048);
            na3 = *(const f16x8*)(p + 3072);
            nsq = *(const float4*)(sqb + cbase0 + (it + 1) * 16 + quad * 4);
        }
        f32x4 acc = {0.f, 0.f, 0.f, 0.f};
        acc = MFMA16(a0, bh0, acc);
        acc = MFMA16(a1, bh1, acc);
        acc = MFMA16(a0, bl0, acc);
        acc = MFMA16(a1, bl1, acc);
        acc = MFMA16(a2, bh0, acc);
        acc = MFMA16(a3, bh1, acc);
        int c0 = cbase0 + it * 16 + quad * 4;  // lane's 4 cands (row=quad*4+r)
        #pragma unroll
        for (int r = 0; r < 4; ++r) {
            float sc = fmaf(2.f, acc[r],
                            -((r == 0) ? sqv.x : (r == 1) ? sqv.y
                                       : (r == 2) ? sqv.z : sqv.w));
            if (sc > d[0]) {                   // cheap append to pending queue
                #pragma unroll
                for (int j = 0; j < PQ; ++j) {
                    bool sel = (pc == j);
                    pv[j] = sel ? sc : pv[j];
                    pi[j] = sel ? (c0 + r) : pi[j];
                }
                ++pc;
            }
            if (__any(pc == PQ)) {             // drain all lanes in parallel
                #pragma unroll
                for (int j = 0; j < PQ; ++j)
                    if (j < pc && pv[j] > d[0]) sorted_insert(d, id, pv[j], pi[j]);
                pc = 0;
            }
        }
    }
    #pragma unroll
    for (int j = 0; j < PQ; ++j)               // final flush
        if (j < pc && pv[j] > d[0]) sorted_insert(d, id, pv[j], pi[j]);

    // in-wave quad-merge tournament via shuffles: 2,3 -> 0,1 then 1 -> 0
    #pragma unroll 1
    for (int step = 0; step < 2; ++step) {
        int off = (step == 0) ? 32 : 16;
        bool active = (step == 0) ? (quad < 2) : (quad == 0);
        for (int j = KNN - 1; j >= 0; --j) {   // descending; early-exit
            float rv = __shfl(d[j], lane + off, 64);
            int   ri = __shfl(id[j], lane + off, 64);
            bool ins = active && (rv > d[0]);
            if (!__any(ins)) break;
            if (ins) sorted_insert(d, id, rv, ri);
        }
    }
    if (lane < 16) {
        size_t rr = (size_t)b * N + rb * 64 + w * 16 + lane;
        float* po = pdg + (rr * 2 + h) * KNN;
        int*   qo = pig + (rr * 2 + h) * KNN;
        #pragma unroll
        for (int j = 0; j < KNN; ++j) { po[j] = d[j]; qo[j] = id[j]; }
    }
}

// -------- K2b: merge the 2 sorted half-lists per query -> knn indices
__global__ __launch_bounds__(128) void k_merge(const float* __restrict__ pdg,
                                               const int* __restrict__ pig,
                                               int* __restrict__ knn) {
    __shared__ float sd[128][41];
    __shared__ int   si[128][41];
    int t = threadIdx.x;
    size_t rr = (size_t)blockIdx.x * 128 + t;
    const float* pr = pdg + rr * (2 * KNN);
    const int*   qr = pig + rr * (2 * KNN);
    #pragma unroll
    for (int j = 0; j < 2 * KNN; ++j) { sd[t][j] = pr[j]; si[t][j] = qr[j]; }
    int i = KNN - 1, j = KNN - 1;
    int* op = knn + rr * KNN;
    for (int o = 0; o < KNN; ++o) {
        bool t0 = (j < 0) || (i >= 0 && sd[t][i] >= sd[t][KNN + j]);
        op[o] = t0 ? si[t][i] : si[t][KNN + j];
        if (t0) --i; else --j;
    }
}

// -------- K3: out[b][o][n] = leaky(scale*(a[n][o] + max_k bvec[idx_k][o]) + bias)
__global__ __launch_bounds__(256) void k_out(const float* __restrict__ av,
                                             const float* __restrict__ bv,
                                             const int* __restrict__ knn,
                                             const float* __restrict__ gamma,
                                             const float* __restrict__ beta,
                                             const float* __restrict__ rmean,
                                             const float* __restrict__ rvar,
                                             float* __restrict__ out) {
    __shared__ float lds[64][65];
    int b    = blockIdx.x >> 6;
    int n0   = (blockIdx.x & 63) << 6;
    int lane = threadIdx.x & 63;
    int w    = __builtin_amdgcn_readfirstlane((int)(threadIdx.x >> 6));
    int o    = lane;
    float scale = gamma[o] * rsqrtf(rvar[o] + BN_EPS);
    float bias  = fmaf(-rmean[o], scale, beta[o]);
    const float* bvb = bv + (size_t)b * N * O;
    for (int i = 0; i < 16; ++i) {
        int n = n0 + w * 16 + i;
        const int* kn = knn + ((size_t)b * N + n) * KNN;
        float mx = -3.4e38f, mn = 3.4e38f;
        #pragma unroll
        for (int j = 0; j < KNN; ++j) {
            float v = bvb[(size_t)kn[j] * O + o];
            mx = fmaxf(mx, v);
            mn = fminf(mn, v);
        }
        float a   = av[((size_t)b * N + n) * O + o];
        float sel = (scale >= 0.f) ? (a + mx) : (a + mn);
        float y   = fmaf(sel, scale, bias);
        y = fmaxf(y, NEG_SLOPE * y);
        lds[o][w * 16 + i] = y;
    }
    __syncthreads();
    int r  = threadIdx.x >> 2;
    int c0 = (threadIdx.x & 3) << 4;
    float* ob = out + (size_t)b * O * N + (size_t)r * N + n0;
    #pragma unroll
    for (int j = 0; j < 16; j += 4) {
        float4 v;
        v.x = lds[r][c0 + j + 0];
        v.y = lds[r][c0 + j + 1];
        v.z = lds[r][c0 + j + 2];
        v.w = lds[r][c0 + j + 3];
        *(float4*)(ob + c0 + j) = v;
    }
}

extern "C" void kernel_launch(void* const* d_in, const int* in_sizes, int n_in,
                              void* d_out, int out_size, void* d_ws, size_t ws_size,
                              hipStream_t stream) {
    const float* x     = (const float*)d_in[0];
    const float* W     = (const float*)d_in[1];
    const float* gamma = (const float*)d_in[2];
    const float* beta  = (const float*)d_in[3];
    const float* rmean = (const float*)d_in[4];
    const float* rvar  = (const float*)d_in[5];
    float* out = (float*)d_out;

    char* wsb = (char*)d_ws;
    float* Xt  = (float*)(wsb);                 //  8 MB
    float* sqn = (float*)(wsb + 8388608);       //  128 KB
    float* av  = (float*)(wsb + 8519680);       //  8 MB
    float* bvv = (float*)(wsb + 16908288);      //  8 MB
    int*   knn = (int*)  (wsb + 25296896);      //  2.5 MB
    char*  AHL =         (wsb + 27918336);      //  8 MB f16 hi/lo frag-major
    float* pdg = (float*)(wsb + 36306944);      //  5.24 MB partial dists
    int*   pig = (int*)  (wsb + 41549824);      //  5.24 MB partial ids

    k_transpose<<<512, 256, 0, stream>>>(x, Xt, sqn, AHL);
    k_ab<<<256, 256, 0, stream>>>(Xt, W, av, bvv);
    k_knn<<<1024, 256, 0, stream>>>(AHL, sqn, pdg, pig);
    k_merge<<<256, 128, 0, stream>>>(pdg, pig, knn);
    k_out<<<512, 256, 0, stream>>>(av, bvv, knn, gamma, beta, rmean, rvar, out);
}